// Round 1
// baseline (506.734 us; speedup 1.0000x reference)
//
#include <hip/hip_runtime.h>
#include <hip/hip_fp16.h>

typedef unsigned short ushort_t;
typedef short bf16x8 __attribute__((ext_vector_type(8)));
typedef float f32x4 __attribute__((ext_vector_type(4)));

#define B_SZ 32
#define T_SZ 256
#define V_SZ 10000
#define E_DIM 300
#define M_DIM 128
#define H_SZ 256

__device__ __forceinline__ ushort_t f2bf(float f) {
  unsigned u = __float_as_uint(f);
  unsigned r = u + 0x7fffu + ((u >> 16) & 1u);
  return (ushort_t)(r >> 16);
}

// ---------------- elementwise cast f32 -> bf16 ----------------
__global__ void k_cast_bf16(const float* __restrict__ in, ushort_t* __restrict__ out, int n) {
  int i = blockIdx.x * blockDim.x + threadIdx.x;
  if (i < n) out[i] = f2bf(in[i]);
}

// ---------------- transpose + cast: out[c][r] = in[r][c], zero-padded ----------------
// MODE 0: bf16 output, MODE 1: f16 output. out dims [Cp][Rp].
template <int MODE>
__global__ void k_transpose_cast(const float* __restrict__ in, ushort_t* __restrict__ out,
                                 int R, int C, int Rp, int Cp) {
  __shared__ float tile[32][33];
  int c0 = blockIdx.x * 32, r0 = blockIdx.y * 32;
  int tx = threadIdx.x, ty = threadIdx.y;  // (32,8)
#pragma unroll
  for (int i = 0; i < 32; i += 8) {
    int r = r0 + ty + i, c = c0 + tx;
    tile[ty + i][tx] = (r < R && c < C) ? in[(size_t)r * C + c] : 0.f;
  }
  __syncthreads();
#pragma unroll
  for (int i = 0; i < 32; i += 8) {
    int c = c0 + ty + i, r = r0 + tx;
    if (c < Cp && r < Rp) {
      float v = tile[tx][ty + i];
      if (MODE == 0) {
        out[(size_t)c * Rp + r] = f2bf(v);
      } else {
        __half h = __float2half(v);
        out[(size_t)c * Rp + r] = *(ushort_t*)&h;
      }
    }
  }
}

// ---------------- fuse: x_b[m][kp] = bf16(xtmp[m][kp] + E[words[m]][kp]) (kp<300), else 0 ----
__global__ void k_xfuse(const float* __restrict__ xtmp, const float* __restrict__ E,
                        const int* __restrict__ words, ushort_t* __restrict__ xb) {
  int m = blockIdx.x;
  int kp = threadIdx.x;  // 320 threads
  int w = words[m];
  float v = 0.f;
  if (kp < E_DIM) v = xtmp[(size_t)m * 320 + kp] + E[(size_t)w * E_DIM + kp];
  xb[(size_t)m * 320 + kp] = f2bf(v);
}

// ---------------- bf16 MFMA GEMM: C[m][n] = sum_k A[m][k]*BT[n][k] + bias[n] ----------------
// A: [M][K] bf16 row-major. BT: [Npad][K] bf16 row-major (pre-transposed B).
// 128x128 tile per block, 4 waves (2x2 of 64x64), BK=64, XOR-swizzled LDS.
__global__ __launch_bounds__(256, 2) void k_gemm_bt(
    const ushort_t* __restrict__ A, const ushort_t* __restrict__ BT,
    const float* __restrict__ bias, float* __restrict__ C,
    int M, int K, int Nreal, int ldc) {
  __shared__ __align__(16) char smem[32768];
  char* As = smem;            // [128 rows][8 slots of 16B], slot = c16 ^ (row&7)
  char* Bs = smem + 16384;
  const int tid = threadIdx.x;
  const int lane = tid & 63;
  const int w = tid >> 6;
  const int wr = w >> 1, wc = w & 1;
  const int m0 = blockIdx.x * 128;   // m-tile fastest-varying: same-B-panel blocks adjacent
  const int n0 = blockIdx.y * 128;

  f32x4 acc[4][4];
#pragma unroll
  for (int i = 0; i < 4; ++i)
#pragma unroll
    for (int j = 0; j < 4; ++j) acc[i][j] = (f32x4){0.f, 0.f, 0.f, 0.f};

  const int srow = tid >> 3;   // 0..31
  const int sc16 = tid & 7;    // 0..7

  for (int k0 = 0; k0 < K; k0 += 64) {
    __syncthreads();
#pragma unroll
    for (int it = 0; it < 4; ++it) {
      int row = srow + it * 32;
      int slot = sc16 ^ (row & 7);
      bf16x8 va = *(const bf16x8*)(A + (size_t)(m0 + row) * K + k0 + sc16 * 8);
      *(bf16x8*)(As + row * 128 + (slot << 4)) = va;
      bf16x8 vb = *(const bf16x8*)(BT + (size_t)(n0 + row) * K + k0 + sc16 * 8);
      *(bf16x8*)(Bs + row * 128 + (slot << 4)) = vb;
    }
    __syncthreads();

    bf16x8 af[4][2], bfr[4][2];
#pragma unroll
    for (int mi = 0; mi < 4; ++mi) {
      int r = wr * 64 + mi * 16 + (lane & 15);
#pragma unroll
      for (int kk = 0; kk < 2; ++kk) {
        int c16 = kk * 4 + (lane >> 4);
        af[mi][kk] = *(const bf16x8*)(As + r * 128 + ((c16 ^ (r & 7)) << 4));
      }
    }
#pragma unroll
    for (int ni = 0; ni < 4; ++ni) {
      int r = wc * 64 + ni * 16 + (lane & 15);
#pragma unroll
      for (int kk = 0; kk < 2; ++kk) {
        int c16 = kk * 4 + (lane >> 4);
        bfr[ni][kk] = *(const bf16x8*)(Bs + r * 128 + ((c16 ^ (r & 7)) << 4));
      }
    }
#pragma unroll
    for (int mi = 0; mi < 4; ++mi)
#pragma unroll
      for (int ni = 0; ni < 4; ++ni)
#pragma unroll
        for (int kk = 0; kk < 2; ++kk)
          acc[mi][ni] = __builtin_amdgcn_mfma_f32_16x16x32_bf16(af[mi][kk], bfr[ni][kk],
                                                                acc[mi][ni], 0, 0, 0);
  }

  // epilogue: D row=(lane>>4)*4+reg, col=lane&15  [verified m89 layout]
  const int rbase = m0 + wr * 64 + (lane >> 4) * 4;
  const int cbase = n0 + wc * 64 + (lane & 15);
#pragma unroll
  for (int ni = 0; ni < 4; ++ni) {
    int n = cbase + ni * 16;
    if (n < Nreal) {
      float bn = bias[n];
#pragma unroll
      for (int mi = 0; mi < 4; ++mi) {
#pragma unroll
        for (int rg = 0; rg < 4; ++rg) {
          int mrow = rbase + mi * 16 + rg;
          C[(size_t)mrow * ldc + n] = acc[mi][ni][rg] + bn;
        }
      }
    }
  }
}

// ---------------- GRU: one block per batch, sync-free recurrence ----------------
// 768 threads, thread j owns column j of U (256 f16 in 128 VGPRs as half2).
// h broadcast from LDS. 2 barriers per step.
__global__ __launch_bounds__(768, 3) void k_gru(
    const float* __restrict__ gx, const ushort_t* __restrict__ UT,
    const float* __restrict__ bu, const int* __restrict__ words,
    ushort_t* __restrict__ seqb) {
  const int b = blockIdx.x;
  const int j = threadIdx.x;
  __shared__ __align__(16) __half hbuf[H_SZ];
  __shared__ float rbuf[H_SZ];
  __shared__ float hnbuf[H_SZ];

  const __half2* Uc = (const __half2*)(UT + (size_t)j * H_SZ);
  __half2 Ur[128];
#pragma unroll
  for (int k = 0; k < 128; ++k) Ur[k] = Uc[k];
  const float bu_j = bu[j];

  float h_old = 0.f;
  if (j < H_SZ) hbuf[j] = __float2half(0.f);
  __syncthreads();

  const float4* hb4 = (const float4*)hbuf;
  for (int t = 0; t < T_SZ; ++t) {
    const size_t row = (size_t)b * T_SZ + t;
    const float* gxr = gx + row * 768;
    const int wv = words[row];
    float gxv = gxr[j];
    float xn = (j < H_SZ) ? gxr[2 * H_SZ + j] : 0.f;

    __half2 a0 = __float2half2_rn(0.f), a1 = a0;
#pragma unroll
    for (int k4 = 0; k4 < 32; ++k4) {
      float4 hv = hb4[k4];  // broadcast read, 8 h values
      const __half2* hp = (const __half2*)(&hv);
      a0 = __hfma2(Ur[4 * k4 + 0], hp[0], a0);
      a1 = __hfma2(Ur[4 * k4 + 1], hp[1], a1);
      a0 = __hfma2(Ur[4 * k4 + 2], hp[2], a0);
      a1 = __hfma2(Ur[4 * k4 + 3], hp[3], a1);
    }
    float2 s0 = __half22float2(a0), s1 = __half22float2(a1);
    float gh = s0.x + s0.y + s1.x + s1.y + bu_j;

    float z = 0.f;
    if (j >= 2 * H_SZ) {
      hnbuf[j - 2 * H_SZ] = gh;                                // hn (incl. bu)
    } else if (j >= H_SZ) {
      rbuf[j - H_SZ] = 1.f / (1.f + __expf(-(gxv + gh)));      // r
    } else {
      z = 1.f / (1.f + __expf(-(gxv + gh)));                   // z
    }
    __syncthreads();
    if (j < H_SZ) {
      float ni = xn + rbuf[j] * hnbuf[j];
      float n = 2.f / (1.f + __expf(-2.f * ni)) - 1.f;         // tanh
      float hnew = (wv != 0) ? (z * h_old + (1.f - z) * n) : h_old;
      h_old = hnew;
      seqb[row * H_SZ + j] = f2bf(hnew);
      hbuf[j] = __float2half(hnew);
    }
    __syncthreads();
  }
}

// ---------------- launcher ----------------
extern "C" void kernel_launch(void* const* d_in, const int* in_sizes, int n_in,
                              void* d_out, int out_size, void* d_ws, size_t ws_size,
                              hipStream_t stream) {
  const int*   words = (const int*)d_in[0];    // [32,256]
  const float* midis = (const float*)d_in[1];  // [32,256,128]
  const float* E     = (const float*)d_in[2];  // [10000,300]
  const float* Wm    = (const float*)d_in[3];  // [128,300]
  const float* bm    = (const float*)d_in[4];  // [300]
  const float* Wx    = (const float*)d_in[5];  // [300,768]
  const float* bx    = (const float*)d_in[6];  // [768]
  const float* U     = (const float*)d_in[7];  // [256,768]
  const float* bu    = (const float*)d_in[8];  // [768]
  const float* Wo    = (const float*)d_in[9];  // [256,10000]
  const float* bo    = (const float*)d_in[10]; // [10000]
  float* out = (float*)d_out;

  const int MT = B_SZ * T_SZ;  // 8192
  size_t off = 0;
  auto alloc = [&](size_t bytes) -> void* {
    void* p = (char*)d_ws + off;
    off += (bytes + 255) & ~(size_t)255;
    return p;
  };
  ushort_t* mid_b = (ushort_t*)alloc((size_t)MT * 128 * 2);
  ushort_t* WmT   = (ushort_t*)alloc((size_t)384 * 128 * 2);
  float*    xtmp  = (float*)   alloc((size_t)MT * 320 * 4);
  ushort_t* x_b   = (ushort_t*)alloc((size_t)MT * 320 * 2);
  ushort_t* WxT   = (ushort_t*)alloc((size_t)768 * 320 * 2);
  float*    gx    = (float*)   alloc((size_t)MT * 768 * 4);
  ushort_t* UT    = (ushort_t*)alloc((size_t)768 * 256 * 2);
  ushort_t* seq_b = (ushort_t*)alloc((size_t)MT * 256 * 2);
  ushort_t* WoT   = (ushort_t*)alloc((size_t)10112 * 256 * 2);
  (void)ws_size;

  // prep: casts + transposes
  k_cast_bf16<<<(MT * 128 + 255) / 256, 256, 0, stream>>>(midis, mid_b, MT * 128);
  k_transpose_cast<0><<<dim3(12, 4),  dim3(32, 8), 0, stream>>>(Wm, WmT, 128, 300, 128, 384);
  k_transpose_cast<0><<<dim3(24, 10), dim3(32, 8), 0, stream>>>(Wx, WxT, 300, 768, 320, 768);
  k_transpose_cast<0><<<dim3(316, 8), dim3(32, 8), 0, stream>>>(Wo, WoT, 256, 10000, 256, 10112);
  k_transpose_cast<1><<<dim3(24, 8),  dim3(32, 8), 0, stream>>>(U, UT, 256, 768, 256, 768);

  // xtmp = midis @ Wm + bm   (M=8192, K=128, Npad=384, Nreal=300, ldc=320)
  k_gemm_bt<<<dim3(64, 3), 256, 0, stream>>>(mid_b, WmT, bm, xtmp, MT, 128, 300, 320);
  // x_b = bf16(xtmp + E[words]) with k-pad zeros
  k_xfuse<<<MT, 320, 0, stream>>>(xtmp, E, words, x_b);
  // gx = x @ Wx + bx   (K=320, N=768)
  k_gemm_bt<<<dim3(64, 6), 256, 0, stream>>>(x_b, WxT, bx, gx, MT, 320, 768, 768);
  // GRU -> seq_b (bf16)
  k_gru<<<B_SZ, 768, 0, stream>>>(gx, UT, bu, words, seq_b);
  // logits = seq @ Wo + bo   (K=256, Npad=10112, Nreal=10000)
  k_gemm_bt<<<dim3(64, 79), 256, 0, stream>>>(seq_b, WoT, bo, out, MT, 256, 10000, 10000);
}

// Round 2
// 502.873 us; speedup vs baseline: 1.0077x; 1.0077x over previous
//
#include <hip/hip_runtime.h>
#include <hip/hip_fp16.h>

typedef unsigned short ushort_t;
typedef short bf16x8 __attribute__((ext_vector_type(8)));
typedef float f32x4 __attribute__((ext_vector_type(4)));
typedef _Float16 h2v __attribute__((ext_vector_type(2)));

#define B_SZ 32
#define T_SZ 256
#define V_SZ 10000
#define E_DIM 300
#define M_DIM 128
#define H_SZ 256

__device__ __forceinline__ ushort_t f2bf(float f) {
  unsigned u = __float_as_uint(f);
  unsigned r = u + 0x7fffu + ((u >> 16) & 1u);
  return (ushort_t)(r >> 16);
}

// ---------------- elementwise cast f32 -> bf16 ----------------
__global__ void k_cast_bf16(const float* __restrict__ in, ushort_t* __restrict__ out, int n) {
  int i = blockIdx.x * blockDim.x + threadIdx.x;
  if (i < n) out[i] = f2bf(in[i]);
}

// ---------------- transpose + cast: out[c][r] = in[r][c], zero-padded ----------------
// MODE 0: bf16 output, MODE 1: f16 output. out dims [Cp][Rp].
template <int MODE>
__global__ void k_transpose_cast(const float* __restrict__ in, ushort_t* __restrict__ out,
                                 int R, int C, int Rp, int Cp) {
  __shared__ float tile[32][33];
  int c0 = blockIdx.x * 32, r0 = blockIdx.y * 32;
  int tx = threadIdx.x, ty = threadIdx.y;  // (32,8)
#pragma unroll
  for (int i = 0; i < 32; i += 8) {
    int r = r0 + ty + i, c = c0 + tx;
    tile[ty + i][tx] = (r < R && c < C) ? in[(size_t)r * C + c] : 0.f;
  }
  __syncthreads();
#pragma unroll
  for (int i = 0; i < 32; i += 8) {
    int c = c0 + ty + i, r = r0 + tx;
    if (c < Cp && r < Rp) {
      float v = tile[tx][ty + i];
      if (MODE == 0) {
        out[(size_t)c * Rp + r] = f2bf(v);
      } else {
        __half h = __float2half(v);
        out[(size_t)c * Rp + r] = *(ushort_t*)&h;
      }
    }
  }
}

// ---------------- fuse: x_b[m][kp] = bf16(xtmp[m][kp] + E[words[m]][kp]) (kp<300), else 0 ----
__global__ void k_xfuse(const float* __restrict__ xtmp, const float* __restrict__ E,
                        const int* __restrict__ words, ushort_t* __restrict__ xb) {
  int m = blockIdx.x;
  int kp = threadIdx.x;  // 320 threads
  int w = words[m];
  float v = 0.f;
  if (kp < E_DIM) v = xtmp[(size_t)m * 320 + kp] + E[(size_t)w * E_DIM + kp];
  xb[(size_t)m * 320 + kp] = f2bf(v);
}

// ---------------- bf16 MFMA GEMM: C[m][n] = sum_k A[m][k]*BT[n][k] + bias[n] ----------------
// A: [M][K] bf16 row-major. BT: [Npad][K] bf16 row-major (pre-transposed B).
// 128x128 tile per block, 4 waves (2x2 of 64x64), BK=64, XOR-swizzled LDS.
__global__ __launch_bounds__(256, 2) void k_gemm_bt(
    const ushort_t* __restrict__ A, const ushort_t* __restrict__ BT,
    const float* __restrict__ bias, float* __restrict__ C,
    int M, int K, int Nreal, int ldc) {
  __shared__ __align__(16) char smem[32768];
  char* As = smem;            // [128 rows][8 slots of 16B], slot = c16 ^ (row&7)
  char* Bs = smem + 16384;
  const int tid = threadIdx.x;
  const int lane = tid & 63;
  const int w = tid >> 6;
  const int wr = w >> 1, wc = w & 1;
  const int m0 = blockIdx.x * 128;   // m-tile fastest-varying: same-B-panel blocks adjacent
  const int n0 = blockIdx.y * 128;

  f32x4 acc[4][4];
#pragma unroll
  for (int i = 0; i < 4; ++i)
#pragma unroll
    for (int j = 0; j < 4; ++j) acc[i][j] = (f32x4){0.f, 0.f, 0.f, 0.f};

  const int srow = tid >> 3;   // 0..31
  const int sc16 = tid & 7;    // 0..7

  for (int k0 = 0; k0 < K; k0 += 64) {
    __syncthreads();
#pragma unroll
    for (int it = 0; it < 4; ++it) {
      int row = srow + it * 32;
      int slot = sc16 ^ (row & 7);
      bf16x8 va = *(const bf16x8*)(A + (size_t)(m0 + row) * K + k0 + sc16 * 8);
      *(bf16x8*)(As + row * 128 + (slot << 4)) = va;
      bf16x8 vb = *(const bf16x8*)(BT + (size_t)(n0 + row) * K + k0 + sc16 * 8);
      *(bf16x8*)(Bs + row * 128 + (slot << 4)) = vb;
    }
    __syncthreads();

    bf16x8 af[4][2], bfr[4][2];
#pragma unroll
    for (int mi = 0; mi < 4; ++mi) {
      int r = wr * 64 + mi * 16 + (lane & 15);
#pragma unroll
      for (int kk = 0; kk < 2; ++kk) {
        int c16 = kk * 4 + (lane >> 4);
        af[mi][kk] = *(const bf16x8*)(As + r * 128 + ((c16 ^ (r & 7)) << 4));
      }
    }
#pragma unroll
    for (int ni = 0; ni < 4; ++ni) {
      int r = wc * 64 + ni * 16 + (lane & 15);
#pragma unroll
      for (int kk = 0; kk < 2; ++kk) {
        int c16 = kk * 4 + (lane >> 4);
        bfr[ni][kk] = *(const bf16x8*)(Bs + r * 128 + ((c16 ^ (r & 7)) << 4));
      }
    }
#pragma unroll
    for (int mi = 0; mi < 4; ++mi)
#pragma unroll
      for (int ni = 0; ni < 4; ++ni)
#pragma unroll
        for (int kk = 0; kk < 2; ++kk)
          acc[mi][ni] = __builtin_amdgcn_mfma_f32_16x16x32_bf16(af[mi][kk], bfr[ni][kk],
                                                                acc[mi][ni], 0, 0, 0);
  }

  // epilogue: D row=(lane>>4)*4+reg, col=lane&15  [verified m89 layout]
  const int rbase = m0 + wr * 64 + (lane >> 4) * 4;
  const int cbase = n0 + wc * 64 + (lane & 15);
#pragma unroll
  for (int ni = 0; ni < 4; ++ni) {
    int n = cbase + ni * 16;
    if (n < Nreal) {
      float bn = bias[n];
#pragma unroll
      for (int mi = 0; mi < 4; ++mi) {
#pragma unroll
        for (int rg = 0; rg < 4; ++rg) {
          int mrow = rbase + mi * 16 + rg;
          C[(size_t)mrow * ldc + n] = acc[mi][ni][rg] + bn;
        }
      }
    }
  }
}

// ---------------- GRU: one block per batch, sync-free recurrence ----------------
// 768 threads, thread j owns column j of U (256 f16 in 128 VGPRs as half2).
// h broadcast from LDS (double-buffered). gx prefetched one step ahead.
// words cached in LDS. v_dot2_f32_f16 with 4 f32 accumulators.
__global__ __launch_bounds__(768, 3) void k_gru(
    const float* __restrict__ gx, const ushort_t* __restrict__ UT,
    const float* __restrict__ bu, const int* __restrict__ words,
    ushort_t* __restrict__ seqb) {
  const int b = blockIdx.x;
  const int j = threadIdx.x;
  __shared__ __align__(16) _Float16 hbuf[2][H_SZ];
  __shared__ float rbuf[H_SZ];
  __shared__ float hnbuf[H_SZ];
  __shared__ int words_s[T_SZ];

  const h2v* Uc = (const h2v*)(UT + (size_t)j * H_SZ);
  h2v Ur[128];
#pragma unroll
  for (int k = 0; k < 128; ++k) Ur[k] = Uc[k];
  const float bu_j = bu[j];

  if (j < H_SZ) hbuf[0][j] = (_Float16)0.f;
  if (j < T_SZ) words_s[j] = words[b * T_SZ + j];
  __syncthreads();

  const float* gxp = gx + (size_t)b * T_SZ * 768;
  float gxv = gxp[j];                                  // t=0 inputs
  float xn = (j < H_SZ) ? gxp[2 * H_SZ + j] : 0.f;
  float h_old = 0.f;
  int p = 0;

  for (int t = 0; t < T_SZ; ++t) {
    // prefetch next step's gx while this step computes (hides HBM/L2 latency)
    float gxv_n = 0.f, xn_n = 0.f;
    if (t + 1 < T_SZ) {
      const float* gxr1 = gxp + (size_t)(t + 1) * 768;
      gxv_n = gxr1[j];
      if (j < H_SZ) xn_n = gxr1[2 * H_SZ + j];
    }

    const float4* hb4 = (const float4*)hbuf[p];
    float a0 = 0.f, a1 = 0.f, a2 = 0.f, a3 = 0.f;
#pragma unroll
    for (int k4 = 0; k4 < 32; ++k4) {
      float4 hv = hb4[k4];  // broadcast read: 8 h values (f16)
      const h2v* hp = (const h2v*)(&hv);
      a0 = __builtin_amdgcn_fdot2(Ur[4 * k4 + 0], hp[0], a0, false);
      a1 = __builtin_amdgcn_fdot2(Ur[4 * k4 + 1], hp[1], a1, false);
      a2 = __builtin_amdgcn_fdot2(Ur[4 * k4 + 2], hp[2], a2, false);
      a3 = __builtin_amdgcn_fdot2(Ur[4 * k4 + 3], hp[3], a3, false);
    }
    float gh = (a0 + a1) + (a2 + a3) + bu_j;

    float z = 0.f;
    if (j >= 2 * H_SZ) {
      hnbuf[j - 2 * H_SZ] = gh;                                // hn (incl. bu)
    } else if (j >= H_SZ) {
      rbuf[j - H_SZ] = 1.f / (1.f + __expf(-(gxv + gh)));      // r
    } else {
      z = 1.f / (1.f + __expf(-(gxv + gh)));                   // z
    }
    __syncthreads();
    if (j < H_SZ) {
      float ni = xn + rbuf[j] * hnbuf[j];
      float n = 2.f / (1.f + __expf(-2.f * ni)) - 1.f;         // tanh
      float hnew = (words_s[t] != 0) ? (z * h_old + (1.f - z) * n) : h_old;
      h_old = hnew;
      seqb[((size_t)b * T_SZ + t) * H_SZ + j] = f2bf(hnew);
      hbuf[p ^ 1][j] = (_Float16)hnew;
    }
    __syncthreads();
    gxv = gxv_n;
    xn = xn_n;
    p ^= 1;
  }
}

// ---------------- launcher ----------------
extern "C" void kernel_launch(void* const* d_in, const int* in_sizes, int n_in,
                              void* d_out, int out_size, void* d_ws, size_t ws_size,
                              hipStream_t stream) {
  const int*   words = (const int*)d_in[0];    // [32,256]
  const float* midis = (const float*)d_in[1];  // [32,256,128]
  const float* E     = (const float*)d_in[2];  // [10000,300]
  const float* Wm    = (const float*)d_in[3];  // [128,300]
  const float* bm    = (const float*)d_in[4];  // [300]
  const float* Wx    = (const float*)d_in[5];  // [300,768]
  const float* bx    = (const float*)d_in[6];  // [768]
  const float* U     = (const float*)d_in[7];  // [256,768]
  const float* bu    = (const float*)d_in[8];  // [768]
  const float* Wo    = (const float*)d_in[9];  // [256,10000]
  const float* bo    = (const float*)d_in[10]; // [10000]
  float* out = (float*)d_out;

  const int MT = B_SZ * T_SZ;  // 8192
  size_t off = 0;
  auto alloc = [&](size_t bytes) -> void* {
    void* p = (char*)d_ws + off;
    off += (bytes + 255) & ~(size_t)255;
    return p;
  };
  ushort_t* mid_b = (ushort_t*)alloc((size_t)MT * 128 * 2);
  ushort_t* WmT   = (ushort_t*)alloc((size_t)384 * 128 * 2);
  float*    xtmp  = (float*)   alloc((size_t)MT * 320 * 4);
  ushort_t* x_b   = (ushort_t*)alloc((size_t)MT * 320 * 2);
  ushort_t* WxT   = (ushort_t*)alloc((size_t)768 * 320 * 2);
  float*    gx    = (float*)   alloc((size_t)MT * 768 * 4);
  ushort_t* UT    = (ushort_t*)alloc((size_t)768 * 256 * 2);
  ushort_t* seq_b = (ushort_t*)alloc((size_t)MT * 256 * 2);
  ushort_t* WoT   = (ushort_t*)alloc((size_t)10112 * 256 * 2);
  (void)ws_size;

  // prep: casts + transposes
  k_cast_bf16<<<(MT * 128 + 255) / 256, 256, 0, stream>>>(midis, mid_b, MT * 128);
  k_transpose_cast<0><<<dim3(12, 4),  dim3(32, 8), 0, stream>>>(Wm, WmT, 128, 300, 128, 384);
  k_transpose_cast<0><<<dim3(24, 10), dim3(32, 8), 0, stream>>>(Wx, WxT, 300, 768, 320, 768);
  k_transpose_cast<0><<<dim3(316, 8), dim3(32, 8), 0, stream>>>(Wo, WoT, 256, 10000, 256, 10112);
  k_transpose_cast<1><<<dim3(24, 8),  dim3(32, 8), 0, stream>>>(U, UT, 256, 768, 256, 768);

  // xtmp = midis @ Wm + bm   (M=8192, K=128, Npad=384, Nreal=300, ldc=320)
  k_gemm_bt<<<dim3(64, 3), 256, 0, stream>>>(mid_b, WmT, bm, xtmp, MT, 128, 300, 320);
  // x_b = bf16(xtmp + E[words]) with k-pad zeros
  k_xfuse<<<MT, 320, 0, stream>>>(xtmp, E, words, x_b);
  // gx = x @ Wx + bx   (K=320, N=768)
  k_gemm_bt<<<dim3(64, 6), 256, 0, stream>>>(x_b, WxT, bx, gx, MT, 320, 768, 768);
  // GRU -> seq_b (bf16)
  k_gru<<<B_SZ, 768, 0, stream>>>(gx, UT, bu, words, seq_b);
  // logits = seq @ Wo + bo   (K=256, Npad=10112, Nreal=10000)
  k_gemm_bt<<<dim3(64, 79), 256, 0, stream>>>(seq_b, WoT, bo, out, MT, 256, 10000, 10000);
}

// Round 3
// 464.639 us; speedup vs baseline: 1.0906x; 1.0823x over previous
//
#include <hip/hip_runtime.h>
#include <hip/hip_fp16.h>

typedef unsigned short ushort_t;
typedef short bf16x8 __attribute__((ext_vector_type(8)));
typedef float f32x4 __attribute__((ext_vector_type(4)));
typedef _Float16 f16x8 __attribute__((ext_vector_type(8)));

#define B_SZ 32
#define T_SZ 256
#define V_SZ 10000
#define E_DIM 300
#define M_DIM 128
#define H_SZ 256

__device__ __forceinline__ ushort_t f2bf(float f) {
  unsigned u = __float_as_uint(f);
  unsigned r = u + 0x7fffu + ((u >> 16) & 1u);
  return (ushort_t)(r >> 16);
}

// ---------------- elementwise cast f32 -> bf16 ----------------
__global__ void k_cast_bf16(const float* __restrict__ in, ushort_t* __restrict__ out, int n) {
  int i = blockIdx.x * blockDim.x + threadIdx.x;
  if (i < n) out[i] = f2bf(in[i]);
}

// ---------------- transpose + cast: out[c][r] = in[r][c], zero-padded ----------------
// MODE 0: bf16 output, MODE 1: f16 output. out dims [Cp][Rp].
template <int MODE>
__global__ void k_transpose_cast(const float* __restrict__ in, ushort_t* __restrict__ out,
                                 int R, int C, int Rp, int Cp) {
  __shared__ float tile[32][33];
  int c0 = blockIdx.x * 32, r0 = blockIdx.y * 32;
  int tx = threadIdx.x, ty = threadIdx.y;  // (32,8)
#pragma unroll
  for (int i = 0; i < 32; i += 8) {
    int r = r0 + ty + i, c = c0 + tx;
    tile[ty + i][tx] = (r < R && c < C) ? in[(size_t)r * C + c] : 0.f;
  }
  __syncthreads();
#pragma unroll
  for (int i = 0; i < 32; i += 8) {
    int c = c0 + ty + i, r = r0 + tx;
    if (c < Cp && r < Rp) {
      float v = tile[tx][ty + i];
      if (MODE == 0) {
        out[(size_t)c * Rp + r] = f2bf(v);
      } else {
        __half h = __float2half(v);
        out[(size_t)c * Rp + r] = *(ushort_t*)&h;
      }
    }
  }
}

// ---------------- fuse: x_b[m][kp] = bf16(xtmp[m][kp] + E[words[m]][kp]) (kp<300), else 0 ----
__global__ void k_xfuse(const float* __restrict__ xtmp, const float* __restrict__ E,
                        const int* __restrict__ words, ushort_t* __restrict__ xb) {
  int m = blockIdx.x;
  int kp = threadIdx.x;  // 320 threads
  int w = words[m];
  float v = 0.f;
  if (kp < E_DIM) v = xtmp[(size_t)m * 320 + kp] + E[(size_t)w * E_DIM + kp];
  xb[(size_t)m * 320 + kp] = f2bf(v);
}

// ---------------- bf16 MFMA GEMM: C[m][n] = sum_k A[m][k]*BT[n][k] + bias[n] ----------------
// A: [M][K] bf16 row-major. BT: [Npad][K] bf16 row-major (pre-transposed B).
// 128x128 tile per block, 4 waves (2x2 of 64x64), BK=64, XOR-swizzled LDS.
__global__ __launch_bounds__(256, 2) void k_gemm_bt(
    const ushort_t* __restrict__ A, const ushort_t* __restrict__ BT,
    const float* __restrict__ bias, float* __restrict__ C,
    int M, int K, int Nreal, int ldc) {
  __shared__ __align__(16) char smem[32768];
  char* As = smem;            // [128 rows][8 slots of 16B], slot = c16 ^ (row&7)
  char* Bs = smem + 16384;
  const int tid = threadIdx.x;
  const int lane = tid & 63;
  const int w = tid >> 6;
  const int wr = w >> 1, wc = w & 1;
  const int m0 = blockIdx.x * 128;   // m-tile fastest-varying: same-B-panel blocks adjacent
  const int n0 = blockIdx.y * 128;

  f32x4 acc[4][4];
#pragma unroll
  for (int i = 0; i < 4; ++i)
#pragma unroll
    for (int j = 0; j < 4; ++j) acc[i][j] = (f32x4){0.f, 0.f, 0.f, 0.f};

  const int srow = tid >> 3;   // 0..31
  const int sc16 = tid & 7;    // 0..7

  for (int k0 = 0; k0 < K; k0 += 64) {
    __syncthreads();
#pragma unroll
    for (int it = 0; it < 4; ++it) {
      int row = srow + it * 32;
      int slot = sc16 ^ (row & 7);
      bf16x8 va = *(const bf16x8*)(A + (size_t)(m0 + row) * K + k0 + sc16 * 8);
      *(bf16x8*)(As + row * 128 + (slot << 4)) = va;
      bf16x8 vb = *(const bf16x8*)(BT + (size_t)(n0 + row) * K + k0 + sc16 * 8);
      *(bf16x8*)(Bs + row * 128 + (slot << 4)) = vb;
    }
    __syncthreads();

    bf16x8 af[4][2], bfr[4][2];
#pragma unroll
    for (int mi = 0; mi < 4; ++mi) {
      int r = wr * 64 + mi * 16 + (lane & 15);
#pragma unroll
      for (int kk = 0; kk < 2; ++kk) {
        int c16 = kk * 4 + (lane >> 4);
        af[mi][kk] = *(const bf16x8*)(As + r * 128 + ((c16 ^ (r & 7)) << 4));
      }
    }
#pragma unroll
    for (int ni = 0; ni < 4; ++ni) {
      int r = wc * 64 + ni * 16 + (lane & 15);
#pragma unroll
      for (int kk = 0; kk < 2; ++kk) {
        int c16 = kk * 4 + (lane >> 4);
        bfr[ni][kk] = *(const bf16x8*)(Bs + r * 128 + ((c16 ^ (r & 7)) << 4));
      }
    }
#pragma unroll
    for (int mi = 0; mi < 4; ++mi)
#pragma unroll
      for (int ni = 0; ni < 4; ++ni)
#pragma unroll
        for (int kk = 0; kk < 2; ++kk)
          acc[mi][ni] = __builtin_amdgcn_mfma_f32_16x16x32_bf16(af[mi][kk], bfr[ni][kk],
                                                                acc[mi][ni], 0, 0, 0);
  }

  // epilogue: D row=(lane>>4)*4+reg, col=lane&15  [verified m89 layout]
  const int rbase = m0 + wr * 64 + (lane >> 4) * 4;
  const int cbase = n0 + wc * 64 + (lane & 15);
#pragma unroll
  for (int ni = 0; ni < 4; ++ni) {
    int n = cbase + ni * 16;
    if (n < Nreal) {
      float bn = bias[n];
#pragma unroll
      for (int mi = 0; mi < 4; ++mi) {
#pragma unroll
        for (int rg = 0; rg < 4; ++rg) {
          int mrow = rbase + mi * 16 + rg;
          C[(size_t)mrow * ldc + n] = acc[mi][ni][rg] + bn;
        }
      }
    }
  }
}

// ---------------- GRU: MFMA matvec, one block per batch ----------------
// 512 threads = 8 waves. Wave w owns U columns [w*96, w*96+96) as register-resident
// B-fragments (f16). Per step: h (f16, zero-padded to 16 rows in LDS, XOR-swizzled)
// is read as 8 A-fragments per wave, 48 mfma_f32_16x16x32_f16 per wave, gh row 0
// scattered to LDS, then thread j (0..255) computes gates for output j.
__global__ __launch_bounds__(512, 2) void k_gru(
    const float* __restrict__ gx, const ushort_t* __restrict__ UT,
    const float* __restrict__ bu, const int* __restrict__ words,
    ushort_t* __restrict__ seqb) {
  const int b = blockIdx.x;
  const int tid = threadIdx.x;
  const int lane = tid & 63;
  const int w = tid >> 6;  // 0..7

  __shared__ __align__(16) _Float16 hlds[16 * 256];  // rows 1..15 stay zero
  __shared__ float ghbuf[768];
  __shared__ int words_s[T_SZ];

  for (int i = tid; i < 16 * 256; i += 512) hlds[i] = (_Float16)0.f;
  if (tid < T_SZ) words_s[tid] = words[b * T_SZ + tid];

  // B-fragments: Ufrag[ni][kk] elem j = U[kk*32 + (lane>>4)*8 + j][n0 + ni*16 + (lane&15)]
  //            = UT[n0 + ni*16 + (lane&15)][kk*32 + (lane>>4)*8 + j]   (UT: [768][256] f16)
  f16x8 Ufrag[6][8];
  {
    const int n0 = w * 96;
    const ushort_t* src = UT + (size_t)(n0 + (lane & 15)) * 256 + (lane >> 4) * 8;
#pragma unroll
    for (int ni = 0; ni < 6; ++ni) {
#pragma unroll
      for (int kk = 0; kk < 8; ++kk)
        Ufrag[ni][kk] = *(const f16x8*)(src + (size_t)ni * 16 * 256 + kk * 32);
    }
  }
  float buz = 0.f, bur = 0.f, bun = 0.f;
  if (tid < H_SZ) {
    buz = bu[tid];
    bur = bu[H_SZ + tid];
    bun = bu[2 * H_SZ + tid];
  }
  __syncthreads();

  const float* gxp = gx + (size_t)b * T_SZ * 768;
  float gxz = 0.f, gxr = 0.f, gxn = 0.f;
  if (tid < H_SZ) {
    gxz = gxp[tid];
    gxr = gxp[H_SZ + tid];
    gxn = gxp[2 * H_SZ + tid];
  }
  float h_old = 0.f;

  // A-frag LDS address: row=(lane&15), chunk c = kk*4 + (lane>>4), swizzle c ^= (row&7).
  const int arow = lane & 15;
  const int abase = arow * 512;  // bytes (256 f16 per row)
  const int asub = lane >> 4;
  const int aswz = arow & 7;

  for (int t = 0; t < T_SZ; ++t) {
    // prefetch next step's gx under the MFMA phase
    float gxz_n = 0.f, gxr_n = 0.f, gxn_n = 0.f;
    if (t + 1 < T_SZ && tid < H_SZ) {
      const float* g1 = gxp + (size_t)(t + 1) * 768;
      gxz_n = g1[tid];
      gxr_n = g1[H_SZ + tid];
      gxn_n = g1[2 * H_SZ + tid];
    }

    f32x4 acc[6];
#pragma unroll
    for (int ni = 0; ni < 6; ++ni) acc[ni] = (f32x4){0.f, 0.f, 0.f, 0.f};
#pragma unroll
    for (int kk = 0; kk < 8; ++kk) {
      int c = kk * 4 + asub;
      f16x8 afrag = *(const f16x8*)((const char*)hlds + abase + ((c ^ aswz) << 4));
#pragma unroll
      for (int ni = 0; ni < 6; ++ni)
        acc[ni] = __builtin_amdgcn_mfma_f32_16x16x32_f16(afrag, Ufrag[ni][kk], acc[ni], 0, 0, 0);
    }
    // C row 0 = lanes 0..15, reg 0  [m89 layout: row=(lane>>4)*4+reg, col=lane&15]
    if (lane < 16) {
      const int nb = w * 96 + lane;
#pragma unroll
      for (int ni = 0; ni < 6; ++ni) ghbuf[nb + ni * 16] = acc[ni][0];
    }
    __syncthreads();

    if (tid < H_SZ) {
      float hz = ghbuf[tid] + buz;
      float hr = ghbuf[H_SZ + tid] + bur;
      float hn = ghbuf[2 * H_SZ + tid] + bun;
      float z = 1.f / (1.f + __expf(-(gxz + hz)));
      float r = 1.f / (1.f + __expf(-(gxr + hr)));
      float nv = 2.f / (1.f + __expf(-2.f * (gxn + r * hn))) - 1.f;  // tanh
      float hnew = (words_s[t] != 0) ? (z * h_old + (1.f - z) * nv) : h_old;
      h_old = hnew;
      seqb[((size_t)b * T_SZ + t) * H_SZ + tid] = f2bf(hnew);
      hlds[tid] = (_Float16)hnew;  // row 0, chunk swizzle is identity for row 0
    }
    __syncthreads();
    gxz = gxz_n;
    gxr = gxr_n;
    gxn = gxn_n;
  }
}

// ---------------- launcher ----------------
extern "C" void kernel_launch(void* const* d_in, const int* in_sizes, int n_in,
                              void* d_out, int out_size, void* d_ws, size_t ws_size,
                              hipStream_t stream) {
  const int*   words = (const int*)d_in[0];    // [32,256]
  const float* midis = (const float*)d_in[1];  // [32,256,128]
  const float* E     = (const float*)d_in[2];  // [10000,300]
  const float* Wm    = (const float*)d_in[3];  // [128,300]
  const float* bm    = (const float*)d_in[4];  // [300]
  const float* Wx    = (const float*)d_in[5];  // [300,768]
  const float* bx    = (const float*)d_in[6];  // [768]
  const float* U     = (const float*)d_in[7];  // [256,768]
  const float* bu    = (const float*)d_in[8];  // [768]
  const float* Wo    = (const float*)d_in[9];  // [256,10000]
  const float* bo    = (const float*)d_in[10]; // [10000]
  float* out = (float*)d_out;

  const int MT = B_SZ * T_SZ;  // 8192
  size_t off = 0;
  auto alloc = [&](size_t bytes) -> void* {
    void* p = (char*)d_ws + off;
    off += (bytes + 255) & ~(size_t)255;
    return p;
  };
  ushort_t* mid_b = (ushort_t*)alloc((size_t)MT * 128 * 2);
  ushort_t* WmT   = (ushort_t*)alloc((size_t)384 * 128 * 2);
  float*    xtmp  = (float*)   alloc((size_t)MT * 320 * 4);
  ushort_t* x_b   = (ushort_t*)alloc((size_t)MT * 320 * 2);
  ushort_t* WxT   = (ushort_t*)alloc((size_t)768 * 320 * 2);
  float*    gx    = (float*)   alloc((size_t)MT * 768 * 4);
  ushort_t* UT    = (ushort_t*)alloc((size_t)768 * 256 * 2);
  ushort_t* seq_b = (ushort_t*)alloc((size_t)MT * 256 * 2);
  ushort_t* WoT   = (ushort_t*)alloc((size_t)10112 * 256 * 2);
  (void)ws_size;

  // prep: casts + transposes
  k_cast_bf16<<<(MT * 128 + 255) / 256, 256, 0, stream>>>(midis, mid_b, MT * 128);
  k_transpose_cast<0><<<dim3(12, 4),  dim3(32, 8), 0, stream>>>(Wm, WmT, 128, 300, 128, 384);
  k_transpose_cast<0><<<dim3(24, 10), dim3(32, 8), 0, stream>>>(Wx, WxT, 300, 768, 320, 768);
  k_transpose_cast<0><<<dim3(316, 8), dim3(32, 8), 0, stream>>>(Wo, WoT, 256, 10000, 256, 10112);
  k_transpose_cast<1><<<dim3(24, 8),  dim3(32, 8), 0, stream>>>(U, UT, 256, 768, 256, 768);

  // xtmp = midis @ Wm + bm   (M=8192, K=128, Npad=384, Nreal=300, ldc=320)
  k_gemm_bt<<<dim3(64, 3), 256, 0, stream>>>(mid_b, WmT, bm, xtmp, MT, 128, 300, 320);
  // x_b = bf16(xtmp + E[words]) with k-pad zeros
  k_xfuse<<<MT, 320, 0, stream>>>(xtmp, E, words, x_b);
  // gx = x @ Wx + bx   (K=320, N=768)
  k_gemm_bt<<<dim3(64, 6), 256, 0, stream>>>(x_b, WxT, bx, gx, MT, 320, 768, 768);
  // GRU -> seq_b (bf16), MFMA matvec version
  k_gru<<<B_SZ, 512, 0, stream>>>(gx, UT, bu, words, seq_b);
  // logits = seq @ Wo + bo   (K=256, Npad=10112, Nreal=10000)
  k_gemm_bt<<<dim3(64, 79), 256, 0, stream>>>(seq_b, WoT, bo, out, MT, 256, 10000, 10000);
}